// Round 1
// 249.481 us; speedup vs baseline: 1.0448x; 1.0448x over previous
//
#include <hip/hip_runtime.h>
#include <stdint.h>
#include <math.h>

// ---------------------------------------------------------------------------
// Threefry-2x32, 20 rounds — exactly JAX's schedule (jax/_src/prng.py).
// ---------------------------------------------------------------------------
#define TFR(r) { x0 += x1; x1 = (x1 << r) | (x1 >> (32 - r)); x1 ^= x0; }

__host__ __device__ __forceinline__ void tf20(uint32_t ks0, uint32_t ks1, uint32_t ks2,
                                              uint32_t x0, uint32_t x1,
                                              uint32_t& o0, uint32_t& o1) {
  x0 += ks0; x1 += ks1;
  TFR(13) TFR(15) TFR(26) TFR(6)
  x0 += ks1; x1 += ks2 + 1u;
  TFR(17) TFR(29) TFR(16) TFR(24)
  x0 += ks2; x1 += ks0 + 2u;
  TFR(13) TFR(15) TFR(26) TFR(6)
  x0 += ks0; x1 += ks1 + 3u;
  TFR(17) TFR(29) TFR(16) TFR(24)
  x0 += ks1; x1 += ks2 + 4u;
  TFR(13) TFR(15) TFR(26) TFR(6)
  x0 += ks2; x1 += ks0 + 5u;
  o0 = x0; o1 = x1;
}

// Pre-injected variant: caller supplies x0 = c0 + ks0, x1 = c1 + ks1.
// Returns o0 ^ o1 (JAX partitionable fold). Bit-identical to tf20.
__device__ __forceinline__ uint32_t tf20_fold(uint32_t ks0, uint32_t ks1, uint32_t ks2,
                                              uint32_t x0, uint32_t x1) {
  TFR(13) TFR(15) TFR(26) TFR(6)
  x0 += ks1; x1 += ks2 + 1u;
  TFR(17) TFR(29) TFR(16) TFR(24)
  x0 += ks2; x1 += ks0 + 2u;
  TFR(13) TFR(15) TFR(26) TFR(6)
  x0 += ks0; x1 += ks1 + 3u;
  TFR(17) TFR(29) TFR(16) TFR(24)
  x0 += ks1; x1 += ks2 + 4u;
  TFR(13) TFR(15) TFR(26) TFR(6)
  x0 += ks2; x1 += ks0 + 5u;
  return x0 ^ x1;
}

// bits -> uniform [0,1): (bits>>9 | 0x3f800000) bitcast - 1.0f  (JAX _uniform)
__device__ __forceinline__ float bits_to_u01(uint32_t bits) {
  return __uint_as_float((bits >> 9) | 0x3f800000u) - 1.0f;
}

// Native hardware exp2 (v_exp_f32). Only used where bit-exactness vs the
// JAX reference is NOT required (softmax denominator -> cat_lp, tol ~3e-2).
__device__ __forceinline__ float ex2(float z) {
#if defined(__has_builtin)
#if __has_builtin(__builtin_amdgcn_exp2f)
  return __builtin_amdgcn_exp2f(z);
#else
  return exp2f(z);
#endif
#else
  return exp2f(z);
#endif
}

// ---------------------------------------------------------------------------
// One thread per 8x8 window.  grid = 2048 blocks (b*256+hc), block = 256 (wc).
// Outputs (float32, concatenated):
//   [0, 1048576)        kp_xy   (8,256,256,2)  [...,0]=col, [...,1]=row
//   [1048576, 1572864)  log_probs (8,256,256)
//   [1572864, 2097152)  mask     (8,256,256)   1.0 / 0.0
// ---------------------------------------------------------------------------
__global__ __launch_bounds__(256) void kp_kernel(
    const float* __restrict__ x, float* __restrict__ out,
    uint32_t kc0, uint32_t kc1, uint32_t kb0, uint32_t kb1) {
  const int wc = threadIdx.x;
  const int bh = blockIdx.x;          // b*256 + hc
  const int b  = bh >> 8;
  const int hc = bh & 255;

  const float* base = x + ((size_t)(b * 2048) + (size_t)(hc * 8)) * 2048 + (size_t)(wc * 8);

  const uint32_t kc2 = kc0 ^ kc1 ^ 0x1BD11BDAu;
  const uint32_t kb2 = kb0 ^ kb1 ^ 0x1BD11BDAu;
  const uint32_t w   = ((uint32_t)bh << 8) | (uint32_t)wc;  // window flat index
  const uint32_t jb  = w << 6;                               // element base = w*64
  const uint32_t jk1 = jb + kc1;      // counter base with ks1 pre-injected

  const float L2E = 1.4426950408889634f;  // log2(e)

  float m  = -INFINITY;   // running max of v (exact, order-independent)
  float s2 = 0.0f;        // running sum of 2^((v-m)*L2E) == sum exp(v-m)
  float best = -INFINITY; // running max of v + g
  uint32_t bk = 0u;       // argmax k (first-max kept via strict >)

  for (int di = 0; di < 8; ++di) {
    const float4* p = reinterpret_cast<const float4*>(base + (size_t)di * 2048);
    float4 a = p[0];
    float4 c = p[1];
    float vv[8] = {a.x, a.y, a.z, a.w, c.x, c.y, c.z, c.w};

    // --- online softmax merge (exp2-domain, hw v_exp_f32; not decision-critical) ---
    float gm = vv[0];
#pragma unroll
    for (int j = 1; j < 8; ++j) gm = fmaxf(gm, vv[j]);
    float gmL = gm * L2E;
    float gs = 0.0f;
#pragma unroll
    for (int j = 0; j < 8; ++j) gs += ex2(fmaf(vv[j], L2E, -gmL));
    float mn = fmaxf(m, gm);
    s2 = s2 * ex2((m - mn) * L2E) + gs * ex2((gm - mn) * L2E);  // iter0: 0*0=0
    m = mn;

    // --- gumbel + running argmax: BIT-EXACT path (OCML logf matches XLA) ---
#pragma unroll
    for (int j = 0; j < 8; ++j) {
      uint32_t bits = tf20_fold(kc0, kc1, kc2, kc0, jk1 + (uint32_t)(di * 8 + j));
      float u = bits_to_u01(bits);
      u = fmaxf(u, 1.17549435e-38f);        // minval = finfo(f32).tiny
      float wv = logf(-logf(u));            // -gumbel; pv = v - wv == v + g bit-exact
      float pv = vv[j] - wv;
      if (pv > best) { best = pv; bk = (uint32_t)(di * 8 + j); }
    }
  }

  // Reload selected value (L1/L2-hot; latency hidden under bern tf20 below).
  const float sel = base[(size_t)(bk >> 3) * 2048 + (bk & 7u)];

  // --- bernoulli accept: u_b < sigmoid(sel); sigmoid kept in double since the
  //     compare is decision-critical (bit path identical to passing kernel) ---
  uint32_t b0, b1;
  tf20(kb0, kb1, kb2, 0u, w, b0, b1);
  float ub = bits_to_u01(b0 ^ b1);
  double sd = (double)sel;
  double ed = exp(-sd);
  float sigf = (float)(1.0 / (1.0 + ed));
  bool acc = ub < sigf;

  // bern_lp from ed in fp32 (needs only ~1e-5 abs):
  //   log_sigmoid(sel)  = -log1p(exp(-sel)) = -l1
  //   log_sigmoid(-sel) = -(sel + l1)   (softplus identity, no cancellation)
  float l1 = log1pf((float)ed);
  float bern_lp = acc ? -l1 : -(sel + l1);

  // cat_lp = (sel - max) - log(sum exp(v - max))
  float cat_lp = (sel - m) - logf(s2);
  float lp = cat_lp + bern_lp;

  float col = (float)((wc << 3) | (int)(bk & 7u));
  float row = (float)((hc << 3) | (int)(bk >> 3));

  reinterpret_cast<float2*>(out)[w] = make_float2(col, row);
  out[1048576u + w] = lp;
  out[1572864u + w] = acc ? 1.0f : 0.0f;
}

extern "C" void kernel_launch(void* const* d_in, const int* in_sizes, int n_in,
                              void* d_out, int out_size, void* d_ws, size_t ws_size,
                              hipStream_t stream) {
  const float* x = (const float*)d_in[0];
  float* out = (float*)d_out;

  // split(key(42)) — partitionable ("foldlike"):
  //   k_cat = threefry2x32((0,42),(0,0)), k_bern = threefry2x32((0,42),(0,1))
  const uint32_t k0 = 0u, k1 = 42u;
  const uint32_t k2 = k0 ^ k1 ^ 0x1BD11BDAu;
  uint32_t kc0, kc1, kb0, kb1;
  tf20(k0, k1, k2, 0u, 0u, kc0, kc1);
  tf20(k0, k1, k2, 0u, 1u, kb0, kb1);

  kp_kernel<<<2048, 256, 0, stream>>>(x, out, kc0, kc1, kb0, kb1);
}

// Round 2
// 246.658 us; speedup vs baseline: 1.0567x; 1.0114x over previous
//
#include <hip/hip_runtime.h>
#include <stdint.h>
#include <math.h>

// ---------------------------------------------------------------------------
// Threefry-2x32, 20 rounds — exactly JAX's schedule (jax/_src/prng.py).
// ---------------------------------------------------------------------------
#define TFR(r) { x0 += x1; x1 = (x1 << r) | (x1 >> (32 - r)); x1 ^= x0; }

__host__ __device__ __forceinline__ void tf20(uint32_t ks0, uint32_t ks1, uint32_t ks2,
                                              uint32_t x0, uint32_t x1,
                                              uint32_t& o0, uint32_t& o1) {
  x0 += ks0; x1 += ks1;
  TFR(13) TFR(15) TFR(26) TFR(6)
  x0 += ks1; x1 += ks2 + 1u;
  TFR(17) TFR(29) TFR(16) TFR(24)
  x0 += ks2; x1 += ks0 + 2u;
  TFR(13) TFR(15) TFR(26) TFR(6)
  x0 += ks0; x1 += ks1 + 3u;
  TFR(17) TFR(29) TFR(16) TFR(24)
  x0 += ks1; x1 += ks2 + 4u;
  TFR(13) TFR(15) TFR(26) TFR(6)
  x0 += ks2; x1 += ks0 + 5u;
  o0 = x0; o1 = x1;
}

// Pre-injected variant: caller supplies x0 = c0 + ks0, x1 = c1 + ks1.
// Returns o0 ^ o1 (JAX partitionable fold). Bit-identical to tf20.
__device__ __forceinline__ uint32_t tf20_fold(uint32_t ks0, uint32_t ks1, uint32_t ks2,
                                              uint32_t x0, uint32_t x1) {
  TFR(13) TFR(15) TFR(26) TFR(6)
  x0 += ks1; x1 += ks2 + 1u;
  TFR(17) TFR(29) TFR(16) TFR(24)
  x0 += ks2; x1 += ks0 + 2u;
  TFR(13) TFR(15) TFR(26) TFR(6)
  x0 += ks0; x1 += ks1 + 3u;
  TFR(17) TFR(29) TFR(16) TFR(24)
  x0 += ks1; x1 += ks2 + 4u;
  TFR(13) TFR(15) TFR(26) TFR(6)
  x0 += ks2; x1 += ks0 + 5u;
  return x0 ^ x1;
}

// bits -> uniform [0,1): (bits>>9 | 0x3f800000) bitcast - 1.0f  (JAX _uniform)
__device__ __forceinline__ float bits_to_u01(uint32_t bits) {
  return __uint_as_float((bits >> 9) | 0x3f800000u) - 1.0f;
}

// Native hardware transcendentals (trans pipe, ~1 ulp). Used only where the
// result is NOT decision-critical, or where an exactness screen guards it.
__device__ __forceinline__ float ex2(float z) {
#if __has_builtin(__builtin_amdgcn_exp2f)
  return __builtin_amdgcn_exp2f(z);
#else
  return exp2f(z);
#endif
}
__device__ __forceinline__ float lg2(float z) {
#if __has_builtin(__builtin_amdgcn_logf)
  return __builtin_amdgcn_logf(z);   // v_log_f32: log2(z)
#else
  return __log2f(z);
#endif
}

// ---------------------------------------------------------------------------
// One thread per 8x8 window.  grid = 2048 blocks (b*256+hc), block = 256 (wc).
// Outputs (float32, concatenated):
//   [0, 1048576)        kp_xy   (8,256,256,2)  [...,0]=col, [...,1]=row
//   [1048576, 1572864)  log_probs (8,256,256)
//   [1572864, 2097152)  mask     (8,256,256)   1.0 / 0.0
// ---------------------------------------------------------------------------
__global__ __launch_bounds__(256) void kp_kernel(
    const float* __restrict__ x, float* __restrict__ out,
    uint32_t kc0, uint32_t kc1, uint32_t kb0, uint32_t kb1) {
  const int wc = threadIdx.x;
  const int bh = blockIdx.x;          // b*256 + hc
  const int b  = bh >> 8;
  const int hc = bh & 255;

  const float* base = x + ((size_t)(b * 2048) + (size_t)(hc * 8)) * 2048 + (size_t)(wc * 8);

  const uint32_t kc2 = kc0 ^ kc1 ^ 0x1BD11BDAu;
  const uint32_t kb2 = kb0 ^ kb1 ^ 0x1BD11BDAu;
  const uint32_t w   = ((uint32_t)bh << 8) | (uint32_t)wc;  // window flat index
  const uint32_t jk1 = (w << 6) + kc1;  // counter base with ks1 pre-injected

  const float L2E  = 1.4426950408889634f;  // log2(e)
  const float LN2  = 0.69314718f;          // ln(2)
  const float TINY = 1.17549435e-38f;      // finfo(f32).tiny

  // ---- pass 1: global max + gumbel argmax (hw-log approx, two-max screen) ----
  float m = -INFINITY;
  float best = -INFINITY, sec = -INFINITY;
  uint32_t bk = 0u;

  for (int di = 0; di < 8; ++di) {
    const float4* p = reinterpret_cast<const float4*>(base + (size_t)di * 2048);
    float4 a = p[0];
    float4 c = p[1];
    float vv[8] = {a.x, a.y, a.z, a.w, c.x, c.y, c.z, c.w};

#pragma unroll
    for (int j = 0; j < 8; ++j) m = fmaxf(m, vv[j]);

#pragma unroll
    for (int j = 0; j < 8; ++j) {
      uint32_t bits = tf20_fold(kc0, kc1, kc2, kc0, jk1 + (uint32_t)(di * 8 + j));
      float u  = fmaxf(bits_to_u01(bits), TINY);
      float t  = lg2(u) * (-LN2);      // ~ -ln(u), rel err ~2e-7
      float wv = lg2(t) * LN2;         // ~ ln(-ln(u)), abs err ~1.3e-6
      float pv = vv[j] - wv;           // |pv_hat - pv_exact| <= ~4e-6
      bool gt = pv > best;
      sec  = gt ? best : fmaxf(sec, pv);
      best = gt ? pv : best;
      bk   = gt ? (uint32_t)(di * 8 + j) : bk;
    }
  }

  // ---- exactness screen: if top-2 gap within margin, redo with OCML logf ----
  // |pv_hat - pv_exact| <= ~4e-6 per element; margin 1e-4 gives >10x safety.
  // P(gap <= 1e-4) ~ 1e-4/window -> ~50 of 524288 windows take this path.
  if (best - sec <= 1e-4f) {
    float bb = -INFINITY;
    uint32_t bkx = 0u;
    for (int di = 0; di < 8; ++di) {
      const float4* p = reinterpret_cast<const float4*>(base + (size_t)di * 2048);
      float4 a = p[0];
      float4 c = p[1];
      float vv[8] = {a.x, a.y, a.z, a.w, c.x, c.y, c.z, c.w};
#pragma unroll
      for (int j = 0; j < 8; ++j) {
        uint32_t bits = tf20_fold(kc0, kc1, kc2, kc0, jk1 + (uint32_t)(di * 8 + j));
        float u  = fmaxf(bits_to_u01(bits), TINY);
        float wv = logf(-logf(u));     // bit-exact decision path (matches XLA)
        float pv = vv[j] - wv;
        if (pv > bb) { bb = pv; bkx = (uint32_t)(di * 8 + j); }
      }
    }
    bk = bkx;
  }

  // ---- pass 2: softmax denominator vs final max (L1-hot reload, VMEM-only) ----
  const float mL = m * L2E;
  float s2a = 0.0f, s2b = 0.0f;
  for (int di = 0; di < 8; ++di) {
    const float4* p = reinterpret_cast<const float4*>(base + (size_t)di * 2048);
    float4 a = p[0];
    float4 c = p[1];
    s2a += ex2(fmaf(a.x, L2E, -mL));
    s2b += ex2(fmaf(a.y, L2E, -mL));
    s2a += ex2(fmaf(a.z, L2E, -mL));
    s2b += ex2(fmaf(a.w, L2E, -mL));
    s2a += ex2(fmaf(c.x, L2E, -mL));
    s2b += ex2(fmaf(c.y, L2E, -mL));
    s2a += ex2(fmaf(c.z, L2E, -mL));
    s2b += ex2(fmaf(c.w, L2E, -mL));
  }
  const float s2 = s2a + s2b;

  // Reload selected value (L1-hot; latency hidden under bern tf20 below).
  const float sel = base[(size_t)(bk >> 3) * 2048 + (bk & 7u)];

  // --- bernoulli accept: u_b < sigmoid(sel); double path kept (absmax==0) ---
  uint32_t b0, b1;
  tf20(kb0, kb1, kb2, 0u, w, b0, b1);
  float ub = bits_to_u01(b0 ^ b1);
  double sd = (double)sel;
  double ed = exp(-sd);
  float sigf = (float)(1.0 / (1.0 + ed));
  bool acc = ub < sigf;

  // bern_lp from ed in fp32 (needs only ~1e-5 abs):
  float l1 = log1pf((float)ed);
  float bern_lp = acc ? -l1 : -(sel + l1);

  // cat_lp = (sel - max) - log(sum exp(v - max))
  float cat_lp = (sel - m) - logf(s2);
  float lp = cat_lp + bern_lp;

  float col = (float)((wc << 3) | (int)(bk & 7u));
  float row = (float)((hc << 3) | (int)(bk >> 3));

  reinterpret_cast<float2*>(out)[w] = make_float2(col, row);
  out[1048576u + w] = lp;
  out[1572864u + w] = acc ? 1.0f : 0.0f;
}

extern "C" void kernel_launch(void* const* d_in, const int* in_sizes, int n_in,
                              void* d_out, int out_size, void* d_ws, size_t ws_size,
                              hipStream_t stream) {
  const float* x = (const float*)d_in[0];
  float* out = (float*)d_out;

  // split(key(42)) — partitionable ("foldlike"):
  //   k_cat = threefry2x32((0,42),(0,0)), k_bern = threefry2x32((0,42),(0,1))
  const uint32_t k0 = 0u, k1 = 42u;
  const uint32_t k2 = k0 ^ k1 ^ 0x1BD11BDAu;
  uint32_t kc0, kc1, kb0, kb1;
  tf20(k0, k1, k2, 0u, 0u, kc0, kc1);
  tf20(k0, k1, k2, 0u, 1u, kb0, kb1);

  kp_kernel<<<2048, 256, 0, stream>>>(x, out, kc0, kc1, kb0, kb1);
}